// Round 15
// baseline (163.962 us; speedup 1.0000x reference)
//
#include <hip/hip_runtime.h>

#define EMB 64

// ---------- Kernel A: segment boundaries (segment_ids sorted) ----------
__global__ void seg_bounds_kernel(const int* __restrict__ seg,
                                  int* __restrict__ row_start,
                                  int T, int B) {
    int t = blockIdx.x * blockDim.x + threadIdx.x;
    if (t >= T) return;
    int s  = seg[t];
    int sp = (t == 0) ? -1 : seg[t - 1];
    for (int b = sp + 1; b <= s; ++b) row_start[b] = t;
    if (t == T - 1) {
        for (int b = s + 1; b <= B; ++b) row_start[b] = T;
    }
}

// ---------- Kernel Q: f32 -> int4 (per-row symmetric scale) ----------
__global__ __launch_bounds__(256) void cvt_q4_kernel(
    const float* __restrict__ src, uint* __restrict__ dst,
    float* __restrict__ scales, int nrows) {
    const int wave = (int)((blockIdx.x * blockDim.x + threadIdx.x) >> 6);
    const int lane = threadIdx.x & 63;
    const int g = lane >> 3, sub = lane & 7;
    const int r = wave * 8 + g;
    if (r >= nrows) return;

    const float* p = src + (size_t)r * EMB + (sub << 3);
    float e[8];
    #pragma unroll
    for (int k = 0; k < 8; ++k) e[k] = p[k];
    float mx = 0.f;
    #pragma unroll
    for (int k = 0; k < 8; ++k) mx = fmaxf(mx, fabsf(e[k]));
    mx = fmaxf(mx, __shfl_xor(mx, 1, 64));
    mx = fmaxf(mx, __shfl_xor(mx, 2, 64));
    mx = fmaxf(mx, __shfl_xor(mx, 4, 64));

    const float scale = mx * (1.0f / 7.5f);
    const float inv   = (mx > 0.f) ? (7.5f / mx) : 0.f;

    uint w = 0;
    #pragma unroll
    for (int k = 0; k < 8; ++k) {
        int q = (int)rintf(fmaf(e[k], inv, 7.5f));
        q = q < 0 ? 0 : (q > 15 ? 15 : q);
        w |= ((uint)q) << (4 * k);
    }
    dst[(size_t)r * 8 + sub] = w;
    if (sub == 0) scales[r] = scale;
}

// ---------- Kernel B v10: flat-chunk schedule, LDS pe table ----------
// Wave owns rows b0..b0+7; entry range [rs[0], rs[8]) split into 8 equal
// chunks (one per 8-lane group). All 8 rows' pe slices + pesum are staged
// in LDS pre-divergence; row transitions read LDS (exec-safe, unlike
// ds_bpermute which returns garbage from exec-masked lanes). Partials land
// in LDS[row][group]; epilogue reduces. No sort, no padding.
__device__ __forceinline__ float qdot8(uint u, const float4 a, const float4 b) {
    const uint lo = u & 0x0F0F0F0Fu;
    const uint hi = (u >> 4) & 0x0F0F0F0Fu;
    const float e0 = (float)(lo & 0xffu),         e1 = (float)(hi & 0xffu);
    const float e2 = (float)((lo >> 8) & 0xffu),  e3 = (float)((hi >> 8) & 0xffu);
    const float e4 = (float)((lo >> 16) & 0xffu), e5 = (float)((hi >> 16) & 0xffu);
    const float e6 = (float)(lo >> 24),           e7 = (float)(hi >> 24);
    return e0*a.x + e1*a.y + e2*a.z + e3*a.w
         + e4*b.x + e5*b.y + e6*b.z + e7*b.w;
}

__global__ __launch_bounds__(256) void svdpp_main_q4(
    const int*   __restrict__ scientist_ids,
    const int*   __restrict__ paper_ids,
    const int*   __restrict__ flat_papers,
    const int*   __restrict__ row_start,
    const float* __restrict__ scientist_factors,
    const float* __restrict__ paper_factors,
    const uint*  __restrict__ imp_q4,
    const float* __restrict__ imp_scale,
    const float* __restrict__ scientist_bias,
    const float* __restrict__ paper_bias,
    float*       __restrict__ out,
    int B) {
    const int wave = (int)((blockIdx.x * blockDim.x + threadIdx.x) >> 6);
    const int lane = threadIdx.x & 63;
    const int g    = lane >> 3;        // group
    const int sub  = lane & 7;         // dims [8*sub, 8*sub+7]
    const int b0   = wave * 8;
    if (b0 >= B) return;
    const int bown  = b0 + g;
    const bool valid = bown < B;
    const int bcl   = valid ? bown : (B - 1);
    const int w     = (int)(threadIdx.x >> 6);

    __shared__ float lds_part[4][64];
    __shared__ float lds_pe[4][8][8][8];    // [wave][row][sub][dim]
    __shared__ float lds_ps[4][8][8];       // [wave][row][sub]
    float* part = lds_part[w];
    part[lane] = 0.0f;                       // unique slot; same-wave order

    // row boundaries rs[0..8] (coalesced, L1/L2-hot)
    int rs[9];
    #pragma unroll
    for (int jj = 0; jj <= 8; ++jj) {
        int idx = b0 + jj;
        rs[jj] = row_start[idx > B ? B : idx];
    }
    const int S = rs[0], E = rs[8];

    // own-row metadata
    const int sid = scientist_ids[bcl];
    const int pid = paper_ids[bcl];

    const float4* pf = reinterpret_cast<const float4*>(
        paper_factors + ((size_t)pid << 6)) + 2 * sub;
    const float4 pe0 = pf[0];
    const float4 pe1 = pf[1];
    const float pesum = pe0.x + pe0.y + pe0.z + pe0.w
                      + pe1.x + pe1.y + pe1.z + pe1.w;

    // stage pe + pesum into LDS (pre-divergence; every lane owns its slot)
    {
        float* d = lds_pe[w][g][sub];
        *reinterpret_cast<float4*>(d)     = pe0;
        *reinterpret_cast<float4*>(d + 4) = pe1;
        lds_ps[w][g][sub] = pesum;
    }

    const float* sf = scientist_factors + ((size_t)sid << 6) + (sub << 3);
    float se[8];
    #pragma unroll
    for (int k = 0; k < 8; ++k) se[k] = __builtin_nontemporal_load(sf + k);
    const float base = se[0]*pe0.x + se[1]*pe0.y + se[2]*pe0.z + se[3]*pe0.w
                     + se[4]*pe1.x + se[5]*pe1.y + se[6]*pe1.z + se[7]*pe1.w;

    const float sb = __builtin_nontemporal_load(scientist_bias + sid);
    const float pb = __builtin_nontemporal_load(paper_bias + pid);

    // my chunk of the wave's flat entry range
    const int total = E - S;
    const int C = (total + 7) >> 3;
    int e    = S + g * C;
    int eend = e + C;
    if (e > E)    e = E;
    if (eend > E) eend = E;

    // initial row j: last j in [0,7] with rs[j] <= e
    int j = 0;
    #pragma unroll
    for (int k = 1; k < 8; ++k) j += (rs[k] <= e) ? 1 : 0;

    // current row's pe slice + pesum from LDS (exec-safe)
    float4 ca, cb; float psc;
    {
        const float* srcp = lds_pe[w][j][sub];
        ca  = *reinterpret_cast<const float4*>(srcp);
        cb  = *reinterpret_cast<const float4*>(srcp + 4);
        psc = lds_ps[w][j][sub];
    }

    float aA0 = 0.f, aA1 = 0.f, aS = 0.f;
    while (e < eend) {
        const int seg_end = (rs[j + 1] < eend) ? rs[j + 1] : eend;
        for (; e + 4 <= seg_end; e += 4) {
            const int p0 = flat_papers[e];
            const int p1 = flat_papers[e + 1];
            const int p2 = flat_papers[e + 2];
            const int p3 = flat_papers[e + 3];
            const uint u0 = imp_q4[((size_t)p0 << 3) + sub];
            const uint u1 = imp_q4[((size_t)p1 << 3) + sub];
            const uint u2 = imp_q4[((size_t)p2 << 3) + sub];
            const uint u3 = imp_q4[((size_t)p3 << 3) + sub];
            const float s0 = imp_scale[p0];
            const float s1 = imp_scale[p1];
            const float s2 = imp_scale[p2];
            const float s3 = imp_scale[p3];
            aA0 = fmaf(s0, qdot8(u0, ca, cb), aA0);
            aA1 = fmaf(s1, qdot8(u1, ca, cb), aA1);
            aA0 = fmaf(s2, qdot8(u2, ca, cb), aA0);
            aA1 = fmaf(s3, qdot8(u3, ca, cb), aA1);
            aS += (s0 + s1) + (s2 + s3);
        }
        for (; e < seg_end; ++e) {
            const int p = flat_papers[e];
            const uint u = imp_q4[((size_t)p << 3) + sub];
            const float s = imp_scale[p];
            aA0 = fmaf(s, qdot8(u, ca, cb), aA0);
            aS += s;
        }
        if (e < eend) {
            // flush row j: reduce across the group's 8 sub lanes
            float val = (aA0 + aA1) - 7.5f * aS * psc;
            val += __shfl_xor(val, 1, 64);   // group-internal: lanes converged
            val += __shfl_xor(val, 2, 64);
            val += __shfl_xor(val, 4, 64);
            if (sub == 0) part[(j << 3) + g] = val;
            aA0 = aA1 = aS = 0.f;
            ++j;
            while (j < 7 && rs[j + 1] <= e) ++j;
            const float* srcp = lds_pe[w][j][sub];
            ca  = *reinterpret_cast<const float4*>(srcp);
            cb  = *reinterpret_cast<const float4*>(srcp + 4);
            psc = lds_ps[w][j][sub];
        }
    }
    // final flush (zero write if chunk empty — harmless, unique slot)
    {
        float val = (aA0 + aA1) - 7.5f * aS * psc;
        val += __shfl_xor(val, 1, 64);
        val += __shfl_xor(val, 2, 64);
        val += __shfl_xor(val, 4, 64);
        if (sub == 0) part[(j << 3) + g] = val;
    }

    // epilogue: row g's partials live at part[g*8 + 0..7]
    const float tmp = part[(g << 3) + sub];
    const int n = rs[g + 1] - rs[g];
    const float scale = (n > 0) ? rsqrtf((float)n) : 0.0f;
    float v = base + scale * tmp;
    v += __shfl_xor(v, 1, 64);
    v += __shfl_xor(v, 2, 64);
    v += __shfl_xor(v, 4, 64);

    if (sub == 0 && valid) {
        __builtin_nontemporal_store(v + sb + pb + 3.82f, out + bown);
    }
}

// ---------- f32 fallback (ws too small) ----------
__global__ __launch_bounds__(256) void svdpp_main_f32(
    const int*   __restrict__ scientist_ids,
    const int*   __restrict__ paper_ids,
    const int*   __restrict__ flat_papers,
    const int*   __restrict__ row_start,
    const float* __restrict__ scientist_factors,
    const float* __restrict__ paper_factors,
    const float* __restrict__ implicit_factors,
    const float* __restrict__ scientist_bias,
    const float* __restrict__ paper_bias,
    float*       __restrict__ out,
    int B) {
    const int wave = (int)((blockIdx.x * blockDim.x + threadIdx.x) >> 6);
    const int lane = threadIdx.x & 63;
    if (wave >= B) return;
    const int b   = wave;
    const int g   = lane >> 4;
    const int sub = lane & 15;

    const int start = row_start[b];
    const int end   = row_start[b + 1];
    const int n     = end - start;

    float4 accA = make_float4(0.f,0.f,0.f,0.f);
    int i = start;
    for (; i < end; i += 4) {
        const int e = i + g;
        if (e < end) {
            const int p = flat_papers[e];
            const float4 r = *reinterpret_cast<const float4*>(
                implicit_factors + ((size_t)p << 6) + (sub << 2));
            accA.x += r.x; accA.y += r.y; accA.z += r.z; accA.w += r.w;
        }
    }

    const float scale = (n > 0) ? rsqrtf((float)n) : 0.0f;
    const int sid = scientist_ids[b];
    const int pid = paper_ids[b];
    const float4 se = *reinterpret_cast<const float4*>(
        scientist_factors + ((size_t)sid << 6) + (sub << 2));
    const float4 pe = *reinterpret_cast<const float4*>(
        paper_factors + ((size_t)pid << 6) + (sub << 2));

    const float basedot = se.x*pe.x + se.y*pe.y + se.z*pe.z + se.w*pe.w;
    const float tdot    = accA.x*pe.x + accA.y*pe.y + accA.z*pe.z + accA.w*pe.w;
    float v = scale * tdot + ((g == 0) ? basedot : 0.0f);

    #pragma unroll
    for (int off = 1; off < 64; off <<= 1) v += __shfl_xor(v, off, 64);

    if (lane == 0) {
        out[b] = v + scientist_bias[sid] + paper_bias[pid] + 3.82f;
    }
}

extern "C" void kernel_launch(void* const* d_in, const int* in_sizes, int n_in,
                              void* d_out, int out_size, void* d_ws, size_t ws_size,
                              hipStream_t stream) {
    const int* scientist_ids       = (const int*)d_in[0];
    const int* paper_ids           = (const int*)d_in[1];
    const int* flat_papers         = (const int*)d_in[2];
    const int* segment_ids         = (const int*)d_in[3];
    const float* scientist_factors = (const float*)d_in[4];
    const float* paper_factors     = (const float*)d_in[5];
    const float* implicit_factors  = (const float*)d_in[6];
    const float* scientist_bias    = (const float*)d_in[7];
    const float* paper_bias        = (const float*)d_in[8];
    float* out = (float*)d_out;

    const int B      = in_sizes[0];
    const int T      = in_sizes[2];
    const int IMP_N  = in_sizes[6];          // NUM_PAPERS * EMB
    const int NROWS  = IMP_N / EMB;          // NUM_PAPERS

    auto align64 = [](size_t x) { return (x + 63) & ~(size_t)63; };
    size_t off0 = 0;                                   // row_start (B+1 ints)
    size_t off1 = align64(off0 + (size_t)(B + 1) * 4); // imp_q4  (NROWS*32B)
    size_t off2 = align64(off1 + (size_t)NROWS * 32);  // imp_scale (NROWS*4B)
    const size_t need = off2 + (size_t)NROWS * 4;

    int*   row_start  = (int*)((char*)d_ws + off0);
    uint*  imp_q4     = (uint*)((char*)d_ws + off1);
    float* imp_scale  = (float*)((char*)d_ws + off2);

    {
        const int threads = 256;
        const int blocks  = (T + threads - 1) / threads;
        seg_bounds_kernel<<<blocks, threads, 0, stream>>>(segment_ids, row_start, T, B);
    }

    if (ws_size >= need) {
        {
            const int threads = 256;                   // 32 rows per block
            const int blocks  = (NROWS + 31) / 32;
            cvt_q4_kernel<<<blocks, threads, 0, stream>>>(
                implicit_factors, imp_q4, imp_scale, NROWS);
        }
        {
            const int threads = 256;                   // 32 output rows per block
            const int blocks  = (B + 31) / 32;
            svdpp_main_q4<<<blocks, threads, 0, stream>>>(
                scientist_ids, paper_ids, flat_papers, row_start,
                scientist_factors, paper_factors, imp_q4, imp_scale,
                scientist_bias, paper_bias, out, B);
        }
    } else {
        const int threads = 256;
        const int blocks  = (B + 3) / 4;
        svdpp_main_f32<<<blocks, threads, 0, stream>>>(
            scientist_ids, paper_ids, flat_papers, row_start,
            scientist_factors, paper_factors, implicit_factors,
            scientist_bias, paper_bias, out, B);
    }
}

// Round 16
// 113.937 us; speedup vs baseline: 1.4391x; 1.4391x over previous
//
#include <hip/hip_runtime.h>

#define EMB 64

#if defined(__has_builtin)
#if __has_builtin(__builtin_amdgcn_sdot4)
#define USE_SDOT 1
#endif
#endif
#ifndef USE_SDOT
#define USE_SDOT 0
#endif

// ---------- Kernel A: segment boundaries (segment_ids sorted) ----------
__global__ void seg_bounds_kernel(const int* __restrict__ seg,
                                  int* __restrict__ row_start,
                                  int T, int B) {
    int t = blockIdx.x * blockDim.x + threadIdx.x;
    if (t >= T) return;
    int s  = seg[t];
    int sp = (t == 0) ? -1 : seg[t - 1];
    for (int b = sp + 1; b <= s; ++b) row_start[b] = t;
    if (t == T - 1) {
        for (int b = s + 1; b <= B; ++b) row_start[b] = T;
    }
}

// ---------- Kernel Q: f32 -> signed int4 stored excess-8 ----------
// value = s * q',  q' in [-7,7],  stored nibble b = q' + 8 (1..15).
__global__ __launch_bounds__(256) void cvt_q4_kernel(
    const float* __restrict__ src, uint* __restrict__ dst,
    float* __restrict__ scales, int nrows) {
    const int wave = (int)((blockIdx.x * blockDim.x + threadIdx.x) >> 6);
    const int lane = threadIdx.x & 63;
    const int g = lane >> 3, sub = lane & 7;
    const int r = wave * 8 + g;
    if (r >= nrows) return;

    const float* p = src + (size_t)r * EMB + (sub << 3);
    float e[8];
    #pragma unroll
    for (int k = 0; k < 8; ++k) e[k] = p[k];
    float mx = 0.f;
    #pragma unroll
    for (int k = 0; k < 8; ++k) mx = fmaxf(mx, fabsf(e[k]));
    mx = fmaxf(mx, __shfl_xor(mx, 1, 64));
    mx = fmaxf(mx, __shfl_xor(mx, 2, 64));
    mx = fmaxf(mx, __shfl_xor(mx, 4, 64));

    const float scale = mx * (1.0f / 7.0f);
    const float inv   = (mx > 0.f) ? (7.0f / mx) : 0.f;

    uint w = 0;
    #pragma unroll
    for (int k = 0; k < 8; ++k) {
        int q = (int)rintf(e[k] * inv);
        q = q < -7 ? -7 : (q > 7 ? 7 : q);
        w |= ((uint)(q + 8)) << (4 * k);
    }
    dst[(size_t)r * 8 + sub] = w;
    if (sub == 0) scales[r] = scale;
}

// ---------- Kernel B v11: R10 structure + integer sdot4 inner loop ----------
// Wave = 8 groups x 8 lanes; group g owns row wave*8+g; lane sub covers dims
// [8*sub..8*sub+7]. pe quantized to int8 per lane (plo = dims 0,2,4,6;
// phi = dims 1,3,5,7 — matching nibble parity of the q4 word). Per entry:
// IDOT = sdot4(lo,plo, sdot4(hi,phi, -8*sum(qp))) ; A += s_y * (float)IDOT.
__global__ __launch_bounds__(256) void svdpp_main_q4(
    const int*   __restrict__ scientist_ids,
    const int*   __restrict__ paper_ids,
    const int*   __restrict__ flat_papers,
    const int*   __restrict__ row_start,
    const float* __restrict__ scientist_factors,
    const float* __restrict__ paper_factors,
    const uint*  __restrict__ imp_q4,
    const float* __restrict__ imp_scale,
    const float* __restrict__ scientist_bias,
    const float* __restrict__ paper_bias,
    float*       __restrict__ out,
    int B) {
    const int wave = (int)((blockIdx.x * blockDim.x + threadIdx.x) >> 6);
    const int lane = threadIdx.x & 63;
    const int g    = lane >> 3;        // group -> row
    const int sub  = lane & 7;         // dims [8*sub, 8*sub+7]
    const int b    = wave * 8 + g;
    if (b >= B) return;

    const int sid   = __builtin_nontemporal_load(scientist_ids + b);
    const int pid   = __builtin_nontemporal_load(paper_ids + b);
    const int start = row_start[b];
    const int end   = row_start[b + 1];

    // paper row (hot 25.6MB table): plain cached float4 loads
    const float4* pf = reinterpret_cast<const float4*>(
        paper_factors + ((size_t)pid << 6)) + 2 * sub;
    const float4 pe0 = pf[0];
    const float4 pe1 = pf[1];

    // scientist row (zero-reuse 256MB table): scalar nt loads
    const float* sf = scientist_factors + ((size_t)sid << 6) + (sub << 3);
    float se[8];
    #pragma unroll
    for (int k = 0; k < 8; ++k) se[k] = __builtin_nontemporal_load(sf + k);

    const float sb = __builtin_nontemporal_load(scientist_bias + sid);
    const float pb = __builtin_nontemporal_load(paper_bias + pid);

    const float base = se[0]*pe0.x + se[1]*pe0.y + se[2]*pe0.z + se[3]*pe0.w
                     + se[4]*pe1.x + se[5]*pe1.y + se[6]*pe1.z + se[7]*pe1.w;

#if USE_SDOT
    // quantize this lane's 8 pe dims to int8 with per-lane scale
    float pmax = fmaxf(fmaxf(fmaxf(fabsf(pe0.x), fabsf(pe0.y)),
                             fmaxf(fabsf(pe0.z), fabsf(pe0.w))),
                       fmaxf(fmaxf(fabsf(pe1.x), fabsf(pe1.y)),
                             fmaxf(fabsf(pe1.z), fabsf(pe1.w))));
    const float sp   = pmax * (1.0f / 127.0f);
    const float pinv = (pmax > 0.f) ? (127.0f / pmax) : 0.f;
    int qp[8];
    qp[0] = (int)rintf(pe0.x * pinv); qp[1] = (int)rintf(pe0.y * pinv);
    qp[2] = (int)rintf(pe0.z * pinv); qp[3] = (int)rintf(pe0.w * pinv);
    qp[4] = (int)rintf(pe1.x * pinv); qp[5] = (int)rintf(pe1.y * pinv);
    qp[6] = (int)rintf(pe1.z * pinv); qp[7] = (int)rintf(pe1.w * pinv);
    // plo: even-parity nibbles -> dims 0,2,4,6 ; phi: dims 1,3,5,7
    const int plo = (qp[0] & 0xff) | ((qp[2] & 0xff) << 8)
                  | ((qp[4] & 0xff) << 16) | ((qp[6] & 0xff) << 24);
    const int phi = (qp[1] & 0xff) | ((qp[3] & 0xff) << 8)
                  | ((qp[5] & 0xff) << 16) | ((qp[7] & 0xff) << 24);
    const int m8psum = -8 * (qp[0] + qp[1] + qp[2] + qp[3]
                           + qp[4] + qp[5] + qp[6] + qp[7]);

    float A0 = 0.f, A1 = 0.f, A2 = 0.f, A3 = 0.f;
    int e = start;
    for (; e + 4 <= end; e += 4) {
        const int p0 = flat_papers[e];
        const int p1 = flat_papers[e + 1];
        const int p2 = flat_papers[e + 2];
        const int p3 = flat_papers[e + 3];
        const uint u0 = imp_q4[((size_t)p0 << 3) + sub];
        const uint u1 = imp_q4[((size_t)p1 << 3) + sub];
        const uint u2 = imp_q4[((size_t)p2 << 3) + sub];
        const uint u3 = imp_q4[((size_t)p3 << 3) + sub];
        const float s0 = imp_scale[p0];
        const float s1 = imp_scale[p1];
        const float s2 = imp_scale[p2];
        const float s3 = imp_scale[p3];
        const int d0 = __builtin_amdgcn_sdot4((int)(u0 & 0x0F0F0F0Fu), plo,
                       __builtin_amdgcn_sdot4((int)((u0 >> 4) & 0x0F0F0F0Fu), phi, m8psum, false), false);
        const int d1 = __builtin_amdgcn_sdot4((int)(u1 & 0x0F0F0F0Fu), plo,
                       __builtin_amdgcn_sdot4((int)((u1 >> 4) & 0x0F0F0F0Fu), phi, m8psum, false), false);
        const int d2 = __builtin_amdgcn_sdot4((int)(u2 & 0x0F0F0F0Fu), plo,
                       __builtin_amdgcn_sdot4((int)((u2 >> 4) & 0x0F0F0F0Fu), phi, m8psum, false), false);
        const int d3 = __builtin_amdgcn_sdot4((int)(u3 & 0x0F0F0F0Fu), plo,
                       __builtin_amdgcn_sdot4((int)((u3 >> 4) & 0x0F0F0F0Fu), phi, m8psum, false), false);
        A0 = fmaf(s0, (float)d0, A0);
        A1 = fmaf(s1, (float)d1, A1);
        A2 = fmaf(s2, (float)d2, A2);
        A3 = fmaf(s3, (float)d3, A3);
    }
    for (; e < end; ++e) {
        const int p = flat_papers[e];
        const uint u = imp_q4[((size_t)p << 3) + sub];
        const float s = imp_scale[p];
        const int d = __builtin_amdgcn_sdot4((int)(u & 0x0F0F0F0Fu), plo,
                      __builtin_amdgcn_sdot4((int)((u >> 4) & 0x0F0F0F0Fu), phi, m8psum, false), false);
        A0 = fmaf(s, (float)d, A0);
    }
    const float acc = sp * ((A0 + A1) + (A2 + A3));
#else
    // float fallback: value = s*(b-8); acc = sum s*(b.pe) - 8*sum(s)*pesum
    const float pesum = pe0.x + pe0.y + pe0.z + pe0.w
                      + pe1.x + pe1.y + pe1.z + pe1.w;
    float A0 = 0.f, A1 = 0.f, S0 = 0.f, S1 = 0.f;
    int e = start;
    for (; e + 2 <= end; e += 2) {
        const int p0 = flat_papers[e];
        const int p1 = flat_papers[e + 1];
        const uint u0 = imp_q4[((size_t)p0 << 3) + sub];
        const uint u1 = imp_q4[((size_t)p1 << 3) + sub];
        const float s0 = imp_scale[p0];
        const float s1 = imp_scale[p1];
        {
            const uint lo = u0 & 0x0F0F0F0Fu, hi = (u0 >> 4) & 0x0F0F0F0Fu;
            const float d = (float)(lo & 0xffu)*pe0.x + (float)(hi & 0xffu)*pe0.y
                          + (float)((lo >> 8) & 0xffu)*pe0.z + (float)((hi >> 8) & 0xffu)*pe0.w
                          + (float)((lo >> 16) & 0xffu)*pe1.x + (float)((hi >> 16) & 0xffu)*pe1.y
                          + (float)(lo >> 24)*pe1.z + (float)(hi >> 24)*pe1.w;
            A0 = fmaf(s0, d, A0); S0 += s0;
        }
        {
            const uint lo = u1 & 0x0F0F0F0Fu, hi = (u1 >> 4) & 0x0F0F0F0Fu;
            const float d = (float)(lo & 0xffu)*pe0.x + (float)(hi & 0xffu)*pe0.y
                          + (float)((lo >> 8) & 0xffu)*pe0.z + (float)((hi >> 8) & 0xffu)*pe0.w
                          + (float)((lo >> 16) & 0xffu)*pe1.x + (float)((hi >> 16) & 0xffu)*pe1.y
                          + (float)(lo >> 24)*pe1.z + (float)(hi >> 24)*pe1.w;
            A1 = fmaf(s1, d, A1); S1 += s1;
        }
    }
    if (e < end) {
        const int p = flat_papers[e];
        const uint u = imp_q4[((size_t)p << 3) + sub];
        const float s = imp_scale[p];
        const uint lo = u & 0x0F0F0F0Fu, hi = (u >> 4) & 0x0F0F0F0Fu;
        const float d = (float)(lo & 0xffu)*pe0.x + (float)(hi & 0xffu)*pe0.y
                      + (float)((lo >> 8) & 0xffu)*pe0.z + (float)((hi >> 8) & 0xffu)*pe0.w
                      + (float)((lo >> 16) & 0xffu)*pe1.x + (float)((hi >> 16) & 0xffu)*pe1.y
                      + (float)(lo >> 24)*pe1.z + (float)(hi >> 24)*pe1.w;
        A0 = fmaf(s, d, A0); S0 += s;
    }
    const float acc = (A0 + A1) - 8.0f * (S0 + S1) * pesum;
#endif

    const int n = end - start;
    const float scale = (n > 0) ? rsqrtf((float)n) : 0.0f;
    float v = base + scale * acc;

    // reduce within the 8-lane group (lane bits 0..2)
    v += __shfl_xor(v, 1, 64);
    v += __shfl_xor(v, 2, 64);
    v += __shfl_xor(v, 4, 64);

    if (sub == 0) {
        __builtin_nontemporal_store(v + sb + pb + 3.82f, out + b);
    }
}

// ---------- f32 fallback (ws too small) ----------
__global__ __launch_bounds__(256) void svdpp_main_f32(
    const int*   __restrict__ scientist_ids,
    const int*   __restrict__ paper_ids,
    const int*   __restrict__ flat_papers,
    const int*   __restrict__ row_start,
    const float* __restrict__ scientist_factors,
    const float* __restrict__ paper_factors,
    const float* __restrict__ implicit_factors,
    const float* __restrict__ scientist_bias,
    const float* __restrict__ paper_bias,
    float*       __restrict__ out,
    int B) {
    const int wave = (int)((blockIdx.x * blockDim.x + threadIdx.x) >> 6);
    const int lane = threadIdx.x & 63;
    if (wave >= B) return;
    const int b   = wave;
    const int g   = lane >> 4;
    const int sub = lane & 15;

    const int start = row_start[b];
    const int end   = row_start[b + 1];
    const int n     = end - start;

    float4 accA = make_float4(0.f,0.f,0.f,0.f);
    int i = start;
    for (; i < end; i += 4) {
        const int e = i + g;
        if (e < end) {
            const int p = flat_papers[e];
            const float4 r = *reinterpret_cast<const float4*>(
                implicit_factors + ((size_t)p << 6) + (sub << 2));
            accA.x += r.x; accA.y += r.y; accA.z += r.z; accA.w += r.w;
        }
    }

    const float scale = (n > 0) ? rsqrtf((float)n) : 0.0f;
    const int sid = scientist_ids[b];
    const int pid = paper_ids[b];
    const float4 se = *reinterpret_cast<const float4*>(
        scientist_factors + ((size_t)sid << 6) + (sub << 2));
    const float4 pe = *reinterpret_cast<const float4*>(
        paper_factors + ((size_t)pid << 6) + (sub << 2));

    const float basedot = se.x*pe.x + se.y*pe.y + se.z*pe.z + se.w*pe.w;
    const float tdot    = accA.x*pe.x + accA.y*pe.y + accA.z*pe.z + accA.w*pe.w;
    float v = scale * tdot + ((g == 0) ? basedot : 0.0f);

    #pragma unroll
    for (int off = 1; off < 64; off <<= 1) v += __shfl_xor(v, off, 64);

    if (lane == 0) {
        out[b] = v + scientist_bias[sid] + paper_bias[pid] + 3.82f;
    }
}

extern "C" void kernel_launch(void* const* d_in, const int* in_sizes, int n_in,
                              void* d_out, int out_size, void* d_ws, size_t ws_size,
                              hipStream_t stream) {
    const int* scientist_ids       = (const int*)d_in[0];
    const int* paper_ids           = (const int*)d_in[1];
    const int* flat_papers         = (const int*)d_in[2];
    const int* segment_ids         = (const int*)d_in[3];
    const float* scientist_factors = (const float*)d_in[4];
    const float* paper_factors     = (const float*)d_in[5];
    const float* implicit_factors  = (const float*)d_in[6];
    const float* scientist_bias    = (const float*)d_in[7];
    const float* paper_bias        = (const float*)d_in[8];
    float* out = (float*)d_out;

    const int B      = in_sizes[0];
    const int T      = in_sizes[2];
    const int IMP_N  = in_sizes[6];          // NUM_PAPERS * EMB
    const int NROWS  = IMP_N / EMB;          // NUM_PAPERS

    auto align64 = [](size_t x) { return (x + 63) & ~(size_t)63; };
    size_t off0 = 0;                                   // row_start (B+1 ints)
    size_t off1 = align64(off0 + (size_t)(B + 1) * 4); // imp_q4  (NROWS*32B)
    size_t off2 = align64(off1 + (size_t)NROWS * 32);  // imp_scale (NROWS*4B)
    const size_t need = off2 + (size_t)NROWS * 4;

    int*   row_start  = (int*)((char*)d_ws + off0);
    uint*  imp_q4     = (uint*)((char*)d_ws + off1);
    float* imp_scale  = (float*)((char*)d_ws + off2);

    {
        const int threads = 256;
        const int blocks  = (T + threads - 1) / threads;
        seg_bounds_kernel<<<blocks, threads, 0, stream>>>(segment_ids, row_start, T, B);
    }

    if (ws_size >= need) {
        {
            const int threads = 256;                   // 32 rows per block
            const int blocks  = (NROWS + 31) / 32;
            cvt_q4_kernel<<<blocks, threads, 0, stream>>>(
                implicit_factors, imp_q4, imp_scale, NROWS);
        }
        {
            const int threads = 256;                   // 32 output rows per block
            const int blocks  = (B + 31) / 32;
            svdpp_main_q4<<<blocks, threads, 0, stream>>>(
                scientist_ids, paper_ids, flat_papers, row_start,
                scientist_factors, paper_factors, imp_q4, imp_scale,
                scientist_bias, paper_bias, out, B);
        }
    } else {
        const int threads = 256;
        const int blocks  = (B + 3) / 4;
        svdpp_main_f32<<<blocks, threads, 0, stream>>>(
            scientist_ids, paper_ids, flat_papers, row_start,
            scientist_factors, paper_factors, implicit_factors,
            scientist_bias, paper_bias, out, B);
    }
}